// Round 14
// baseline (139.847 us; speedup 1.0000x reference)
//
#include <hip/hip_runtime.h>
#include <hip/hip_bf16.h>
#include <stdint.h>

// SmoothLoss: total = (1/24) * sum over 24 offsets of mean( exp(-||dx||^2/200) * ||dy||_1 )
// x = rgb2ycbcr(input) (bias cancels in diffs), y = output. 12 offsets, weight 2x.
// R13 = R11 champion structure, Phase B + Phase C datapath rewritten over pixel
// PAIRS as ext_vector f32x2 -> CDNA4 packed-FP32 (v_pk_fma/add/mul/max_f32).
// |t| = max(t,-t) = one v_pk_max_f32 with neg modifier (VOP3P has no abs mod).
// exp stays scalar v_exp_f32 (no pk transcendental); neg folds into its input.
// Structure (unchanged from R11): 512 thr / 8 waves; TH=4 own rows + 2 halo;
// COLS=520; symmetric all-wave gload_lds staging; poisoned halos (plane0=1e19
// -> v_exp flushes to 0, no bounds checks); Phase B in-place ycbcr with
// K2=sqrt(0.005/ln2) baked in; Phase C windows via ds_read_b128 at 16B lane
// stride; LDS 74,880B -> 2 blocks/CU; s_setprio around compute clusters.

#define B_ 16
#define H_ 512
#define W_ 512
#define HW_ (H_ * W_)
#define CHW_ (3 * HW_)

#define TH 4          // own rows per block
#define ROWS 6        // TH + 2 bottom halo
#define COLS 520      // 4 pad | 512 | 4 pad ; img col j <-> lds col j+4
#define NTHREADS 512
#define POISON 1e19f
#define K2 0.08493218049364766f  // sqrt(0.005 / ln(2))

typedef float f2 __attribute__((ext_vector_type(2)));

__global__ void zero_out_kernel(float* p) { p[0] = 0.0f; }

__device__ __forceinline__ void gload16(const float* gsrc, float* ldst) {
  __builtin_amdgcn_global_load_lds(
      (const __attribute__((address_space(1))) void*)gsrc,
      (__attribute__((address_space(3))) void*)ldst, 16, 0, 0);
}

__device__ __forceinline__ f2 pabs(f2 t) {            // v_pk_max_f32 with neg
  return __builtin_elementwise_max(t, -t);
}

// O[plane][q]: q <-> img col j0+q (8 floats: own 4 px + 4 right)
template <int DW>
__device__ __forceinline__ f2 contrib0(const float (&O)[6][8]) {
  const float scale = 2.0f / (24.0f * (float)B_ * (float)H_ * (float)(W_ - DW));
  f2 acc2 = {0.0f, 0.0f};
#pragma unroll
  for (int m = 0; m < 2; ++m) {
    const int p0 = 2 * m, p1 = 2 * m + 1;
    f2 d0 = (f2){O[0][p0], O[0][p1]} - (f2){O[0][p0 + DW], O[0][p1 + DW]};
    f2 d1 = (f2){O[1][p0], O[1][p1]} - (f2){O[1][p0 + DW], O[1][p1 + DW]};
    f2 d2 = (f2){O[2][p0], O[2][p1]} - (f2){O[2][p0 + DW], O[2][p1 + DW]};
    f2 q = d0 * d0;
    q += d1 * d1;
    q += d2 * d2;
    f2 w = {__builtin_amdgcn_exp2f(-q.x), __builtin_amdgcn_exp2f(-q.y)};
    f2 t3 = (f2){O[3][p0], O[3][p1]} - (f2){O[3][p0 + DW], O[3][p1 + DW]};
    f2 t4 = (f2){O[4][p0], O[4][p1]} - (f2){O[4][p0 + DW], O[4][p1 + DW]};
    f2 t5 = (f2){O[5][p0], O[5][p1]} - (f2){O[5][p0 + DW], O[5][p1 + DW]};
    f2 l1 = pabs(t3) + pabs(t4) + pabs(t5);
    acc2 += w * l1;
  }
  return (f2){scale, scale} * acc2;
}

// N[plane][q]: q <-> img col j0-4+q (12 floats)
template <int DH, int DW>
__device__ __forceinline__ f2 contribN(const float (&O)[6][8],
                                       const float (&N)[6][12]) {
  constexpr int AW = DW < 0 ? -DW : DW;
  const float scale =
      2.0f / (24.0f * (float)B_ * (float)(H_ - DH) * (float)(W_ - AW));
  f2 acc2 = {0.0f, 0.0f};
#pragma unroll
  for (int m = 0; m < 2; ++m) {
    const int p0 = 2 * m, p1 = 2 * m + 1;
    const int n0 = p0 + 4 + DW, n1 = p1 + 4 + DW;
    f2 d0 = (f2){O[0][p0], O[0][p1]} - (f2){N[0][n0], N[0][n1]};
    f2 d1 = (f2){O[1][p0], O[1][p1]} - (f2){N[1][n0], N[1][n1]};
    f2 d2 = (f2){O[2][p0], O[2][p1]} - (f2){N[2][n0], N[2][n1]};
    f2 q = d0 * d0;
    q += d1 * d1;
    q += d2 * d2;
    f2 w = {__builtin_amdgcn_exp2f(-q.x), __builtin_amdgcn_exp2f(-q.y)};
    f2 t3 = (f2){O[3][p0], O[3][p1]} - (f2){N[3][n0], N[3][n1]};
    f2 t4 = (f2){O[4][p0], O[4][p1]} - (f2){N[4][n0], N[4][n1]};
    f2 t5 = (f2){O[5][p0], O[5][p1]} - (f2){N[5][n0], N[5][n1]};
    f2 l1 = pabs(t3) + pabs(t4) + pabs(t5);
    acc2 += w * l1;
  }
  return (f2){scale, scale} * acc2;
}

__global__ __launch_bounds__(NTHREADS, 4) void smooth_loss_kernel(
    const float* __restrict__ in, const float* __restrict__ outp,
    float* __restrict__ result) {
  __shared__ alignas(16) float lds[6][ROWS][COLS];  // 74,880 B
  __shared__ float wsum[8];

  const int tid = threadIdx.x;
  const int wv = tid >> 6;     // 0..7
  const int lane = tid & 63;
  const int by = blockIdx.x;   // 0..127 row tile
  const int b = blockIdx.y;    // 0..15 batch
  const int ibase = by * TH;

  const float* inb = in + (size_t)b * CHW_;
  const float* outb = outp + (size_t)b * CHW_;

  // ---- Phase A: async stage. 72 wave-chunks = 6 rows x 6 planes x 2 halves ----
#pragma unroll
  for (int k = 0; k < 9; ++k) {
    int wc = wv + 8 * k;            // wave-uniform
    int r = wc / 12;
    int rem = wc - 12 * r;
    int p = rem >> 1;
    int h = rem & 1;
    if (ibase + r < H_) {
      const float* src =
          (p < 3 ? inb + (size_t)p * HW_ : outb + (size_t)(p - 3) * HW_) +
          (size_t)(ibase + r) * W_ + 256 * h + 4 * lane;
      gload16(src, &lds[p][r][4 + 256 * h]);
    }
  }

  // ---- poison halo columns (all rows): plane0 = POISON, others = 0 ----
  if (tid < 288) {
    int p = tid / 48;
    int rem = tid - 48 * p;
    int r = rem >> 3;
    int ci = rem & 7;
    int col = ci < 4 ? ci : 512 + ci;
    lds[p][r][col] = (p == 0) ? POISON : 0.0f;
  }
  // ---- poison out-of-range bottom halo rows (only last tile) ----
  if (ibase + TH >= H_) {
    for (int c = tid; c < 6 * 2 * COLS; c += NTHREADS) {
      int p = c / (2 * COLS);
      int rem = c - p * (2 * COLS);
      int r = 4 + rem / COLS;
      int col = rem % COLS;
      lds[p][r][col] = (p == 0) ? POISON : 0.0f;
    }
  }

  __syncthreads();  // drains gload_lds (vmcnt) + ds_writes

  // ---- Phase B: in-place rgb -> ycbcr, coefficients x K2, packed f32 ----
  {
#pragma unroll
    for (int k = 0; k < 2; ++k) {
      int c = tid + NTHREADS * k;   // 780 float4-items = 6 rows x 130
      if (c < ROWS * 130) {
        int r = c / 130;
        int q4 = c - 130 * r;
        int col = 4 * q4;
        float4 rr = *(const float4*)&lds[0][r][col];
        float4 gg = *(const float4*)&lds[1][r][col];
        float4 bb = *(const float4*)&lds[2][r][col];
        f2 r0 = {rr.x, rr.y}, r1 = {rr.z, rr.w};
        f2 g0 = {gg.x, gg.y}, g1 = {gg.z, gg.w};
        f2 b0 = {bb.x, bb.y}, b1 = {bb.z, bb.w};
        f2 x0a = (0.257f * K2) * r0 + (0.564f * K2) * g0 + (0.098f * K2) * b0;
        f2 x0b = (0.257f * K2) * r1 + (0.564f * K2) * g1 + (0.098f * K2) * b1;
        f2 x1a = (-0.148f * K2) * r0 + (-0.291f * K2) * g0 + (0.439f * K2) * b0;
        f2 x1b = (-0.148f * K2) * r1 + (-0.291f * K2) * g1 + (0.439f * K2) * b1;
        f2 x2a = (0.439f * K2) * r0 + (-0.368f * K2) * g0 + (-0.071f * K2) * b0;
        f2 x2b = (0.439f * K2) * r1 + (-0.368f * K2) * g1 + (-0.071f * K2) * b1;
        *(float4*)&lds[0][r][col] = make_float4(x0a.x, x0a.y, x0b.x, x0b.y);
        *(float4*)&lds[1][r][col] = make_float4(x1a.x, x1a.y, x1b.x, x1b.y);
        *(float4*)&lds[2][r][col] = make_float4(x2a.x, x2a.y, x2b.x, x2b.y);
      }
    }
  }

  __syncthreads();

  // ---- Phase C: wave (half,row); lane handles img cols j0..j0+3 ----
  const int half = wv >> 2;       // 0..1
  const int row = wv & 3;         // own row within tile
  const int j0 = 256 * half + 4 * lane;

  f2 accv = {0.0f, 0.0f};
  float O[6][8];
#pragma unroll
  for (int p6 = 0; p6 < 6; ++p6) {
    *(float4*)&O[p6][0] = *(const float4*)&lds[p6][row][j0 + 4];
    *(float4*)&O[p6][4] = *(const float4*)&lds[p6][row][j0 + 8];
  }

  __builtin_amdgcn_s_setprio(1);
  accv += contrib0<1>(O);
  accv += contrib0<2>(O);
  __builtin_amdgcn_s_setprio(0);

  {
    float N[6][12];
#pragma unroll
    for (int p6 = 0; p6 < 6; ++p6) {
      *(float4*)&N[p6][0] = *(const float4*)&lds[p6][row + 1][j0];
      *(float4*)&N[p6][4] = *(const float4*)&lds[p6][row + 1][j0 + 4];
      *(float4*)&N[p6][8] = *(const float4*)&lds[p6][row + 1][j0 + 8];
    }
    __builtin_amdgcn_s_setprio(1);
    accv += contribN<1, -2>(O, N);
    accv += contribN<1, -1>(O, N);
    accv += contribN<1, 0>(O, N);
    accv += contribN<1, 1>(O, N);
    accv += contribN<1, 2>(O, N);
    __builtin_amdgcn_s_setprio(0);
  }
  {
    float N[6][12];
#pragma unroll
    for (int p6 = 0; p6 < 6; ++p6) {
      *(float4*)&N[p6][0] = *(const float4*)&lds[p6][row + 2][j0];
      *(float4*)&N[p6][4] = *(const float4*)&lds[p6][row + 2][j0 + 4];
      *(float4*)&N[p6][8] = *(const float4*)&lds[p6][row + 2][j0 + 8];
    }
    __builtin_amdgcn_s_setprio(1);
    accv += contribN<2, -2>(O, N);
    accv += contribN<2, -1>(O, N);
    accv += contribN<2, 0>(O, N);
    accv += contribN<2, 1>(O, N);
    accv += contribN<2, 2>(O, N);
    __builtin_amdgcn_s_setprio(0);
  }

  float acc = accv.x + accv.y;

  // ---- reduction ----
#pragma unroll
  for (int o = 32; o > 0; o >>= 1) acc += __shfl_down(acc, o, 64);
  if (lane == 0) wsum[wv] = acc;
  __syncthreads();
  if (tid == 0) {
    float s = 0.0f;
#pragma unroll
    for (int wq = 0; wq < 8; ++wq) s += wsum[wq];
    atomicAdd(result, s);
  }
}

extern "C" void kernel_launch(void* const* d_in, const int* in_sizes, int n_in,
                              void* d_out, int out_size, void* d_ws, size_t ws_size,
                              hipStream_t stream) {
  const float* in = (const float*)d_in[0];
  const float* outp = (const float*)d_in[1];
  float* res = (float*)d_out;

  zero_out_kernel<<<1, 1, 0, stream>>>(res);

  dim3 grid(H_ / TH, B_, 1);  // (128, 16)
  smooth_loss_kernel<<<grid, NTHREADS, 0, stream>>>(in, outp, res);
}

// Round 15
// 48.941 us; speedup vs baseline: 2.8575x; 2.8575x over previous
//
#include <hip/hip_runtime.h>
#include <hip/hip_bf16.h>
#include <stdint.h>

// SmoothLoss: total = (1/24) * sum over 24 offsets of mean( exp(-||dx||^2/200) * ||dy||_1 )
// x = rgb2ycbcr(input) (bias cancels in diffs), y = output. 12 offsets, weight 2x.
// R14 = R11 champion with ONE change: Phase-C N-windows read as exactly the 8
// needed floats (img cols j0-2..j0+5, lds cols j0+2..j0+9, 8B-aligned) via
// 4x float2 per plane (-> ds_read2_b64 pairs) instead of 12 floats via 3x b128.
// Cuts Phase-C LDS traffic 768 -> 576 B/thread (~25%); LDS pipe was ~80% duty.
// Structure (R11): 512 thr / 8 waves; TH=4 own rows + 2 halo; COLS=520;
// symmetric all-wave gload_lds staging; poisoned halos (plane0=1e19 -> v_exp
// flushes to 0, no bounds checks); Phase B in-place ycbcr with K2 baked in;
// raw __builtin_amdgcn_exp2f; s_setprio around compute clusters; 2 blocks/CU.

#define B_ 16
#define H_ 512
#define W_ 512
#define HW_ (H_ * W_)
#define CHW_ (3 * HW_)

#define TH 4          // own rows per block
#define ROWS 6        // TH + 2 bottom halo
#define COLS 520      // 4 pad | 512 | 4 pad ; img col j <-> lds col j+4
#define NTHREADS 512
#define POISON 1e19f
#define K2 0.08493218049364766f  // sqrt(0.005 / ln(2))

__global__ void zero_out_kernel(float* p) { p[0] = 0.0f; }

__device__ __forceinline__ void gload16(const float* gsrc, float* ldst) {
  __builtin_amdgcn_global_load_lds(
      (const __attribute__((address_space(1))) void*)gsrc,
      (__attribute__((address_space(3))) void*)ldst, 16, 0, 0);
}

// O[plane][q]: q <-> img col j0+q (8 floats: own 4 px + 4 right)
template <int DW>
__device__ __forceinline__ float contrib0(const float (&O)[6][8]) {
  const float scale = 2.0f / (24.0f * (float)B_ * (float)H_ * (float)(W_ - DW));
  float s = 0.0f;
#pragma unroll
  for (int p = 0; p < 4; ++p) {
    float d0 = O[0][p] - O[0][p + DW];
    float d1 = O[1][p] - O[1][p + DW];
    float d2 = O[2][p] - O[2][p + DW];
    float nq = -(d0 * d0 + d1 * d1 + d2 * d2);
    float wgt = __builtin_amdgcn_exp2f(nq);   // raw v_exp_f32
    float l1 = fabsf(O[3][p] - O[3][p + DW]) + fabsf(O[4][p] - O[4][p + DW]) +
               fabsf(O[5][p] - O[5][p + DW]);
    s += wgt * l1;
  }
  return scale * s;
}

// N[plane][q]: q <-> img col j0-2+q (8 floats, exact window)
template <int DH, int DW>
__device__ __forceinline__ float contribN(const float (&O)[6][8],
                                          const float (&N)[6][8]) {
  constexpr int AW = DW < 0 ? -DW : DW;
  const float scale =
      2.0f / (24.0f * (float)B_ * (float)(H_ - DH) * (float)(W_ - AW));
  float s = 0.0f;
#pragma unroll
  for (int p = 0; p < 4; ++p) {
    const int ni = p + 2 + DW;   // 0..7
    float d0 = O[0][p] - N[0][ni];
    float d1 = O[1][p] - N[1][ni];
    float d2 = O[2][p] - N[2][ni];
    float nq = -(d0 * d0 + d1 * d1 + d2 * d2);
    float wgt = __builtin_amdgcn_exp2f(nq);   // raw v_exp_f32
    float l1 = fabsf(O[3][p] - N[3][ni]) + fabsf(O[4][p] - N[4][ni]) +
               fabsf(O[5][p] - N[5][ni]);
    s += wgt * l1;
  }
  return scale * s;
}

__global__ __launch_bounds__(NTHREADS, 4) void smooth_loss_kernel(
    const float* __restrict__ in, const float* __restrict__ outp,
    float* __restrict__ result) {
  __shared__ alignas(16) float lds[6][ROWS][COLS];  // 74,880 B
  __shared__ float wsum[8];

  const int tid = threadIdx.x;
  const int wv = tid >> 6;     // 0..7
  const int lane = tid & 63;
  const int by = blockIdx.x;   // 0..127 row tile
  const int b = blockIdx.y;    // 0..15 batch
  const int ibase = by * TH;

  const float* inb = in + (size_t)b * CHW_;
  const float* outb = outp + (size_t)b * CHW_;

  // ---- Phase A: async stage. 72 wave-chunks = 6 rows x 6 planes x 2 halves ----
#pragma unroll
  for (int k = 0; k < 9; ++k) {
    int wc = wv + 8 * k;            // wave-uniform
    int r = wc / 12;
    int rem = wc - 12 * r;
    int p = rem >> 1;
    int h = rem & 1;
    if (ibase + r < H_) {
      const float* src =
          (p < 3 ? inb + (size_t)p * HW_ : outb + (size_t)(p - 3) * HW_) +
          (size_t)(ibase + r) * W_ + 256 * h + 4 * lane;
      gload16(src, &lds[p][r][4 + 256 * h]);
    }
  }

  // ---- poison halo columns (all rows): plane0 = POISON, others = 0 ----
  if (tid < 288) {
    int p = tid / 48;
    int rem = tid - 48 * p;
    int r = rem >> 3;
    int ci = rem & 7;
    int col = ci < 4 ? ci : 512 + ci;
    lds[p][r][col] = (p == 0) ? POISON : 0.0f;
  }
  // ---- poison out-of-range bottom halo rows (only last tile) ----
  if (ibase + TH >= H_) {
    for (int c = tid; c < 6 * 2 * COLS; c += NTHREADS) {
      int p = c / (2 * COLS);
      int rem = c - p * (2 * COLS);
      int r = 4 + rem / COLS;
      int col = rem % COLS;
      lds[p][r][col] = (p == 0) ? POISON : 0.0f;
    }
  }

  __syncthreads();  // drains gload_lds (vmcnt) + ds_writes

  // ---- Phase B: in-place rgb -> ycbcr, coefficients x K2 ----
  {
#pragma unroll
    for (int k = 0; k < 2; ++k) {
      int c = tid + NTHREADS * k;   // 780 float4-items = 6 rows x 130
      if (c < ROWS * 130) {
        int r = c / 130;
        int q4 = c - 130 * r;
        int col = 4 * q4;
        float4 rr = *(const float4*)&lds[0][r][col];
        float4 gg = *(const float4*)&lds[1][r][col];
        float4 bb = *(const float4*)&lds[2][r][col];
        float rv[4] = {rr.x, rr.y, rr.z, rr.w};
        float gv[4] = {gg.x, gg.y, gg.z, gg.w};
        float bv[4] = {bb.x, bb.y, bb.z, bb.w};
        float x0[4], x1[4], x2[4];
#pragma unroll
        for (int m = 0; m < 4; ++m) {
          x0[m] = (0.257f * K2) * rv[m] + (0.564f * K2) * gv[m] + (0.098f * K2) * bv[m];
          x1[m] = (-0.148f * K2) * rv[m] + (-0.291f * K2) * gv[m] + (0.439f * K2) * bv[m];
          x2[m] = (0.439f * K2) * rv[m] + (-0.368f * K2) * gv[m] + (-0.071f * K2) * bv[m];
        }
        *(float4*)&lds[0][r][col] = make_float4(x0[0], x0[1], x0[2], x0[3]);
        *(float4*)&lds[1][r][col] = make_float4(x1[0], x1[1], x1[2], x1[3]);
        *(float4*)&lds[2][r][col] = make_float4(x2[0], x2[1], x2[2], x2[3]);
      }
    }
  }

  __syncthreads();

  // ---- Phase C: wave (half,row); lane handles img cols j0..j0+3 ----
  const int half = wv >> 2;       // 0..1
  const int row = wv & 3;         // own row within tile
  const int j0 = 256 * half + 4 * lane;
  // own img col j <-> lds col j+4; O at lds cols j0+4..j0+11 (16B aligned);
  // N window img cols j0-2..j0+5 = lds cols j0+2..j0+9 (8B aligned)

  float acc = 0.0f;
  float O[6][8];
#pragma unroll
  for (int p6 = 0; p6 < 6; ++p6) {
    *(float4*)&O[p6][0] = *(const float4*)&lds[p6][row][j0 + 4];
    *(float4*)&O[p6][4] = *(const float4*)&lds[p6][row][j0 + 8];
  }

  __builtin_amdgcn_s_setprio(1);
  acc += contrib0<1>(O);
  acc += contrib0<2>(O);
  __builtin_amdgcn_s_setprio(0);

  {
    float N[6][8];
#pragma unroll
    for (int p6 = 0; p6 < 6; ++p6) {
      *(float2*)&N[p6][0] = *(const float2*)&lds[p6][row + 1][j0 + 2];
      *(float2*)&N[p6][2] = *(const float2*)&lds[p6][row + 1][j0 + 4];
      *(float2*)&N[p6][4] = *(const float2*)&lds[p6][row + 1][j0 + 6];
      *(float2*)&N[p6][6] = *(const float2*)&lds[p6][row + 1][j0 + 8];
    }
    __builtin_amdgcn_s_setprio(1);
    acc += contribN<1, -2>(O, N);
    acc += contribN<1, -1>(O, N);
    acc += contribN<1, 0>(O, N);
    acc += contribN<1, 1>(O, N);
    acc += contribN<1, 2>(O, N);
    __builtin_amdgcn_s_setprio(0);
  }
  {
    float N[6][8];
#pragma unroll
    for (int p6 = 0; p6 < 6; ++p6) {
      *(float2*)&N[p6][0] = *(const float2*)&lds[p6][row + 2][j0 + 2];
      *(float2*)&N[p6][2] = *(const float2*)&lds[p6][row + 2][j0 + 4];
      *(float2*)&N[p6][4] = *(const float2*)&lds[p6][row + 2][j0 + 6];
      *(float2*)&N[p6][6] = *(const float2*)&lds[p6][row + 2][j0 + 8];
    }
    __builtin_amdgcn_s_setprio(1);
    acc += contribN<2, -2>(O, N);
    acc += contribN<2, -1>(O, N);
    acc += contribN<2, 0>(O, N);
    acc += contribN<2, 1>(O, N);
    acc += contribN<2, 2>(O, N);
    __builtin_amdgcn_s_setprio(0);
  }

  // ---- reduction ----
#pragma unroll
  for (int o = 32; o > 0; o >>= 1) acc += __shfl_down(acc, o, 64);
  if (lane == 0) wsum[wv] = acc;
  __syncthreads();
  if (tid == 0) {
    float s = 0.0f;
#pragma unroll
    for (int wq = 0; wq < 8; ++wq) s += wsum[wq];
    atomicAdd(result, s);
  }
}

extern "C" void kernel_launch(void* const* d_in, const int* in_sizes, int n_in,
                              void* d_out, int out_size, void* d_ws, size_t ws_size,
                              hipStream_t stream) {
  const float* in = (const float*)d_in[0];
  const float* outp = (const float*)d_in[1];
  float* res = (float*)d_out;

  zero_out_kernel<<<1, 1, 0, stream>>>(res);

  dim3 grid(H_ / TH, B_, 1);  // (128, 16)
  smooth_loss_kernel<<<grid, NTHREADS, 0, stream>>>(in, outp, res);
}